// Round 6
// baseline (914.793 us; speedup 1.0000x reference)
//
#include <hip/hip_runtime.h>

#define H 128
#define H2 256
#define NODE_IN 32
#define BN_EPS 1e-5f

typedef __bf16 bf16x8 __attribute__((ext_vector_type(8)));
typedef __bf16 bf16x4 __attribute__((ext_vector_type(4)));
typedef float f32x4 __attribute__((ext_vector_type(4)));

#define MFMA(a, b, c) __builtin_amdgcn_mfma_f32_16x16x32_bf16(a, b, c, 0, 0, 0)

// ---------------------------------------------------------------------------
// W1 [L][128][256] -> W1t [L][256][128] bf16 ; W2 [L][256][128] -> W2t [L][128][256] bf16
__global__ __launch_bounds__(256) void convert_weights_kernel(
    const float* __restrict__ W1, const float* __restrict__ W2,
    __bf16* __restrict__ W1t, __bf16* __restrict__ W2t, int L)
{
    int idx = blockIdx.x * 256 + threadIdx.x;
    int per = H * H2;
    int total = L * per;
    if (idx < total) {
        int l = idx / per, r = idx % per;
        int k = r / H2, n = r % H2;
        W1t[(size_t)l * per + (size_t)n * H + k] = (__bf16)W1[idx];
    } else if (idx < 2 * total) {
        int j = idx - total;
        int l = j / per, r = j % per;
        int k = r / H, n = r % H;
        W2t[(size_t)l * per + (size_t)n * H2 + k] = (__bf16)W2[j];
    }
}

// ---------------------------------------------------------------------------
// h0 = x @ emb_W + emb_b  (bf16 out)
__global__ __launch_bounds__(256) void embed_kernel(
    const float* __restrict__ x, const float* __restrict__ W,
    const float* __restrict__ bias, __bf16* __restrict__ h, int N)
{
    __shared__ float xs[16][NODE_IN + 4];
    int row0 = blockIdx.x * 16;
    int t = threadIdx.x;
    if (t < 128) {
        int r = t >> 3, c4 = t & 7;
        int gr = row0 + r;
        float4 v = make_float4(0.f, 0.f, 0.f, 0.f);
        if (gr < N) v = *(const float4*)&x[(size_t)gr * NODE_IN + c4 * 4];
        *(float4*)&xs[r][c4 * 4] = v;
    }
    __syncthreads();
    int c = t & (H - 1);
    int rg = t >> 7;
    int r0 = rg * 8;
    float acc[8] = {0, 0, 0, 0, 0, 0, 0, 0};
    for (int k = 0; k < NODE_IN; ++k) {
        float w = W[k * H + c];
#pragma unroll
        for (int r = 0; r < 8; ++r) acc[r] += xs[r0 + r][k] * w;
    }
    float bb = bias[c];
#pragma unroll
    for (int r = 0; r < 8; ++r) {
        int gr = row0 + r0 + r;
        if (gr < N) h[(size_t)gr * H + c] = (__bf16)(acc[r] + bb);
    }
}

// ---------------------------------------------------------------------------
// CSR build
__global__ __launch_bounds__(256) void hist_kernel(
    const int* __restrict__ dst, int* __restrict__ deg, int E)
{
    int e = blockIdx.x * 256 + threadIdx.x;
    if (e < E) atomicAdd(&deg[dst[e]], 1);
}

__global__ __launch_bounds__(256) void scan_partial_kernel(
    const int* __restrict__ deg, int* __restrict__ bsum, int N)
{
    __shared__ int red[256];
    int b = blockIdx.x, t = threadIdx.x;
    int base = b * 2048 + t * 8;
    int s = 0;
#pragma unroll
    for (int i = 0; i < 8; ++i) { int idx = base + i; if (idx < N) s += deg[idx]; }
    red[t] = s;
    __syncthreads();
    for (int d = 128; d > 0; d >>= 1) {
        if (t < d) red[t] += red[t + d];
        __syncthreads();
    }
    if (t == 0) bsum[b] = red[0];
}

__global__ __launch_bounds__(256) void scan_bsum_kernel(
    int* __restrict__ bsum, int* __restrict__ total, int numB)
{
    __shared__ int ts[256];
    int t = threadIdx.x;
    int v = (t < numB) ? bsum[t] : 0;
    ts[t] = v;
    __syncthreads();
    for (int d = 1; d < 256; d <<= 1) {
        int u = (t >= d) ? ts[t - d] : 0;
        __syncthreads();
        ts[t] += u;
        __syncthreads();
    }
    if (t < numB) bsum[t] = ts[t] - v;
    if (t == 255) *total = ts[255];
}

__global__ __launch_bounds__(256) void scan_apply_kernel(
    const int* __restrict__ deg, const int* __restrict__ bsum,
    int* __restrict__ offp, int* __restrict__ cursor, int N)
{
    __shared__ int ts[256];
    int b = blockIdx.x, t = threadIdx.x;
    int base = b * 2048 + t * 8;
    int loc[8];
    int s = 0;
#pragma unroll
    for (int i = 0; i < 8; ++i) {
        int idx = base + i;
        loc[i] = (idx < N) ? deg[idx] : 0;
        s += loc[i];
    }
    ts[t] = s;
    __syncthreads();
    for (int d = 1; d < 256; d <<= 1) {
        int u = (t >= d) ? ts[t - d] : 0;
        __syncthreads();
        ts[t] += u;
        __syncthreads();
    }
    int run = bsum[b] + ts[t] - s;
#pragma unroll
    for (int i = 0; i < 8; ++i) {
        int idx = base + i;
        if (idx < N) { offp[idx] = run; cursor[idx] = run; }
        run += loc[i];
    }
}

__global__ __launch_bounds__(256) void fill_kernel(
    const int* __restrict__ src, const int* __restrict__ dst,
    int* __restrict__ cursor, int* __restrict__ srclist, int E)
{
    int e = blockIdx.x * 256 + threadIdx.x;
    if (e < E) {
        int pos = atomicAdd(&cursor[dst[e]], 1);
        srclist[pos] = src[e];
    }
}

// ---------------------------------------------------------------------------
// zg[v] = bf16( f(hin[v]) + sum_{nbr} f(hin[src]) ); f = BN?relu(v*sc+sh):v
// 16 lanes per node, bf16x8 (16B)/lane. Output is 16B-chunk XOR-swizzled:
// chunk' = chunk ^ (v & 7)  (consumed by mlp's LDS reads).
template <int BN>
__global__ __launch_bounds__(256) void gather_kernel(
    const __bf16* __restrict__ hin, const float* __restrict__ ss,
    const int* __restrict__ offp, const int* __restrict__ srclist,
    char* __restrict__ zg, int N)
{
    int gid = blockIdx.x * 256 + threadIdx.x;
    int v = gid >> 4;
    if (v >= N) return;
    int c16 = gid & 15;
    float sc[8], sh[8];
    if (BN) {
#pragma unroll
        for (int j = 0; j < 8; ++j) { sc[j] = ss[c16 * 8 + j]; sh[j] = ss[H + c16 * 8 + j]; }
    }
    float acc[8];
    bf16x8 sv = *(const bf16x8*)(hin + (size_t)v * H + c16 * 8);
#pragma unroll
    for (int j = 0; j < 8; ++j) {
        float f = (float)sv[j];
        acc[j] = BN ? fmaxf(f * sc[j] + sh[j], 0.f) : f;
    }
    int i0 = offp[v], i1 = offp[v + 1];
    int i = i0;
    for (; i + 1 < i1; i += 2) {
        int s0 = srclist[i], s1 = srclist[i + 1];
        bf16x8 u0 = *(const bf16x8*)(hin + (size_t)s0 * H + c16 * 8);
        bf16x8 u1 = *(const bf16x8*)(hin + (size_t)s1 * H + c16 * 8);
#pragma unroll
        for (int j = 0; j < 8; ++j) {
            float f0 = (float)u0[j], f1 = (float)u1[j];
            if (BN) {
                f0 = fmaxf(f0 * sc[j] + sh[j], 0.f);
                f1 = fmaxf(f1 * sc[j] + sh[j], 0.f);
            }
            acc[j] += f0 + f1;
        }
    }
    if (i < i1) {
        int s0 = srclist[i];
        bf16x8 u0 = *(const bf16x8*)(hin + (size_t)s0 * H + c16 * 8);
#pragma unroll
        for (int j = 0; j < 8; ++j) {
            float f0 = (float)u0[j];
            if (BN) f0 = fmaxf(f0 * sc[j] + sh[j], 0.f);
            acc[j] += f0;
        }
    }
    bf16x8 o;
#pragma unroll
    for (int j = 0; j < 8; ++j) o[j] = (__bf16)acc[j];
    int chunk = c16 ^ (v & 7);
    *(bf16x8*)(zg + (size_t)v * 256 + chunk * 16) = o;
}

// ---------------------------------------------------------------------------
// MLP, one 64-row tile per block, 8 waves (512 thr). Latency hidden by TLP
// (multiple resident blocks), not intra-block pipelining.
// GEMM1 (swapped: A=W1 frags): wave w owns hid cols [w*32,w*32+32), all 64 rows.
// GEMM2 (swapped: A=W2 frags): wave w owns out cols [w*16,w*16+16), all 64 rows.
// hid: 64 rows x 512B, 16B-chunk XOR swizzle (chunk ^ row&7) both sides.
__global__ __launch_bounds__(512, 2) void mlp_mfma_kernel(
    const char* __restrict__ zg, __bf16* __restrict__ zpb,
    const __bf16* __restrict__ W1t, const float* __restrict__ b1l,
    const __bf16* __restrict__ W2t, const float* __restrict__ b2l,
    float* __restrict__ stats, int N)
{
    __shared__ char zt[16384];    // 64 rows x 256B (swizzled zg tile)
    __shared__ char hid[32768];   // 64 rows x 512B (swizzled)

    int tid = threadIdx.x;
    int w = tid >> 6, lane = tid & 63;
    int l15 = lane & 15, kg = lane >> 4;
    int tile = blockIdx.x;

    // ---- stage zt: 2 x (512 thr x 16B) ----
    {
        const char* g = zg + (size_t)tile * 16384 + tid * 16;
        char* l0 = zt + w * 1024;            // wave-uniform; HW adds lane*16
        char* l1 = zt + 8192 + w * 1024;
        __builtin_amdgcn_global_load_lds(
            (const __attribute__((address_space(1))) void*)g,
            (__attribute__((address_space(3))) void*)l0, 16, 0, 0);
        __builtin_amdgcn_global_load_lds(
            (const __attribute__((address_space(1))) void*)(g + 8192),
            (__attribute__((address_space(3))) void*)l1, 16, 0, 0);
    }

    // ---- weight fragments (overlap with zt stage; drained at barrier) ----
    bf16x8 aW1[2][4], aW2[8];
#pragma unroll
    for (int nt = 0; nt < 2; ++nt)
#pragma unroll
        for (int kk = 0; kk < 4; ++kk)
            aW1[nt][kk] = *(const bf16x8*)(W1t + (size_t)(w * 32 + nt * 16 + l15) * H + kk * 32 + kg * 8);
#pragma unroll
    for (int kk = 0; kk < 8; ++kk)
        aW2[kk] = *(const bf16x8*)(W2t + (size_t)(w * 16 + l15) * H2 + kk * 32 + kg * 8);

    float bb1[2][4], bb2[4];
#pragma unroll
    for (int nt = 0; nt < 2; ++nt)
#pragma unroll
        for (int q = 0; q < 4; ++q) bb1[nt][q] = b1l[w * 32 + nt * 16 + kg * 4 + q];
#pragma unroll
    for (int q = 0; q < 4; ++q) bb2[q] = b2l[w * 16 + kg * 4 + q];

    __syncthreads();   // zt ready (vmcnt drained)

    // ---- GEMM1: hid = relu(zg @ W1 + b1) ----
    f32x4 acc1[2][4];
#pragma unroll
    for (int nt = 0; nt < 2; ++nt)
#pragma unroll
        for (int s = 0; s < 4; ++s)
#pragma unroll
            for (int q = 0; q < 4; ++q) acc1[nt][s][q] = 0.f;

#pragma unroll
    for (int kk = 0; kk < 4; ++kk) {
#pragma unroll
        for (int s = 0; s < 4; ++s) {
            int r = s * 16 + l15;
            int c = (kk * 4 + kg) ^ (r & 7);
            bf16x8 b = *(const bf16x8*)(zt + r * 256 + c * 16);
            acc1[0][s] = MFMA(aW1[0][kk], b, acc1[0][s]);
            acc1[1][s] = MFMA(aW1[1][kk], b, acc1[1][s]);
        }
    }
#pragma unroll
    for (int nt = 0; nt < 2; ++nt)
#pragma unroll
        for (int s = 0; s < 4; ++s) {
            bf16x4 hv;
#pragma unroll
            for (int q = 0; q < 4; ++q)
                hv[q] = (__bf16)fmaxf(acc1[nt][s][q] + bb1[nt][q], 0.f);
            int r = s * 16 + l15;
            int u = w * 8 + nt * 4 + kg;   // 8B unit within the 512B row
            int byteoff = r * 512 + (((u >> 1) ^ (r & 7)) << 4) + ((u & 1) << 3);
            *(bf16x4*)(hid + byteoff) = hv;
        }
    __syncthreads();   // hid complete

    // ---- GEMM2: zp = hid @ W2 + b2 ----
    f32x4 acc2[4];
#pragma unroll
    for (int rg = 0; rg < 4; ++rg)
#pragma unroll
        for (int q = 0; q < 4; ++q) acc2[rg][q] = 0.f;

#pragma unroll
    for (int kk = 0; kk < 8; ++kk) {
#pragma unroll
        for (int rg = 0; rg < 4; ++rg) {
            int r = rg * 16 + l15;
            int c = (kk * 4 + kg) ^ (r & 7);
            bf16x8 b = *(const bf16x8*)(hid + r * 512 + c * 16);
            acc2[rg] = MFMA(aW2[kk], b, acc2[rg]);
        }
    }

    // ---- epilogue: store zp (bf16), BN partial stats ----
    float ps[4] = {0.f, 0.f, 0.f, 0.f}, pq[4] = {0.f, 0.f, 0.f, 0.f};
    int rbase = tile * 64;
#pragma unroll
    for (int rg = 0; rg < 4; ++rg) {
        int r = rbase + rg * 16 + l15;
        if (r < N) {
            bf16x4 ov;
#pragma unroll
            for (int q = 0; q < 4; ++q) {
                float vv = acc2[rg][q] + bb2[q];
                ov[q] = (__bf16)vv;
                ps[q] += vv;
                pq[q] += vv * vv;
            }
            *(bf16x4*)(zpb + (size_t)r * H + w * 16 + kg * 4) = ov;
        }
    }
#pragma unroll
    for (int m = 1; m <= 8; m <<= 1) {
#pragma unroll
        for (int q = 0; q < 4; ++q) {
            ps[q] += __shfl_xor(ps[q], m);
            pq[q] += __shfl_xor(pq[q], m);
        }
    }
    if (l15 == 0) {
#pragma unroll
        for (int q = 0; q < 4; ++q) {
            atomicAdd(&stats[w * 16 + kg * 4 + q], ps[q]);
            atomicAdd(&stats[H + w * 16 + kg * 4 + q], pq[q]);
        }
    }
}

// ---------------------------------------------------------------------------
__global__ void bn_finalize_kernel(const float* __restrict__ stats,
                                   const float* __restrict__ gamma,
                                   const float* __restrict__ beta,
                                   float* __restrict__ ss, int N)
{
    int j = threadIdx.x;
    float invN = 1.0f / (float)N;
    float mean = stats[j] * invN;
    float var = stats[H + j] * invN - mean * mean;
    float sc = gamma[j] * rsqrtf(var + BN_EPS);
    ss[j] = sc;
    ss[H + j] = beta[j] - mean * sc;
}

// ---------------------------------------------------------------------------
// out = relu(zpb*scale + shift), bf16 -> fp32
__global__ __launch_bounds__(256) void bn_apply_kernel(
    const __bf16* __restrict__ zpb, const float* __restrict__ ss,
    float* __restrict__ out, int N)
{
    size_t i = (size_t)blockIdx.x * 256 + threadIdx.x;   // 8-elem units
    size_t total = (size_t)N * (H / 8);
    if (i >= total) return;
    int c8 = (int)(i & (H / 8 - 1));
    bf16x8 v = *(const bf16x8*)(zpb + i * 8);
    float4 o0, o1;
    const float* scp = &ss[c8 * 8];
    const float* shp = &ss[H + c8 * 8];
    o0.x = fmaxf((float)v[0] * scp[0] + shp[0], 0.f);
    o0.y = fmaxf((float)v[1] * scp[1] + shp[1], 0.f);
    o0.z = fmaxf((float)v[2] * scp[2] + shp[2], 0.f);
    o0.w = fmaxf((float)v[3] * scp[3] + shp[3], 0.f);
    o1.x = fmaxf((float)v[4] * scp[4] + shp[4], 0.f);
    o1.y = fmaxf((float)v[5] * scp[5] + shp[5], 0.f);
    o1.z = fmaxf((float)v[6] * scp[6] + shp[6], 0.f);
    o1.w = fmaxf((float)v[7] * scp[7] + shp[7], 0.f);
    ((float4*)out)[i * 2] = o0;
    ((float4*)out)[i * 2 + 1] = o1;
}

// ---------------------------------------------------------------------------
static inline char* align_up(char* p, size_t a) {
    return (char*)(((uintptr_t)p + a - 1) & ~(uintptr_t)(a - 1));
}

extern "C" void kernel_launch(void* const* d_in, const int* in_sizes, int n_in,
                              void* d_out, int out_size, void* d_ws, size_t ws_size,
                              hipStream_t stream)
{
    const float* x    = (const float*)d_in[0];
    const int*   ei   = (const int*)d_in[1];
    const float* embW = (const float*)d_in[2];
    const float* embb = (const float*)d_in[3];
    const float* W1   = (const float*)d_in[4];
    const float* b1   = (const float*)d_in[5];
    const float* W2   = (const float*)d_in[6];
    const float* b2   = (const float*)d_in[7];
    const float* gamma= (const float*)d_in[8];
    const float* beta = (const float*)d_in[9];

    int N = in_sizes[0] / NODE_IN;
    int E = in_sizes[1] / 2;
    int L = in_sizes[4] / (H * H2);
    const int* src = ei;
    const int* dst = ei + E;

    int numB = (N + 2047) / 2048;
    int T2 = (N + 63) / 64;          // 64-row tiles

    char* w = (char*)d_ws;
    __bf16* zpb = (__bf16*)w;    w += (size_t)N * H * sizeof(__bf16);
    w = align_up(w, 256);
    char* zgb = w;               w += (size_t)T2 * 16384;
    w = align_up(w, 256);
    __bf16* h0 = (__bf16*)w;     w += (size_t)N * H * sizeof(__bf16);
    w = align_up(w, 256);
    float* statsAll = (float*)w; w += (size_t)L * 2 * H * sizeof(float);
    float* ss = (float*)w;       w += 2 * H * sizeof(float);
    int* deg = (int*)w;          w += (size_t)N * sizeof(int);
    int* offp = (int*)w;         w += (size_t)(N + 1) * sizeof(int);
    int* cursor = (int*)w;       w += (size_t)N * sizeof(int);
    int* bsum = (int*)w;         w += (size_t)numB * sizeof(int);
    int* srcl = (int*)w;         w += (size_t)E * sizeof(int);
    w = align_up(w, 256);
    __bf16* W1t = (__bf16*)w;    w += (size_t)L * H * H2 * sizeof(__bf16);
    w = align_up(w, 256);
    __bf16* W2t = (__bf16*)w;    w += (size_t)L * H * H2 * sizeof(__bf16);

    float* out = (float*)d_out;

    // ---- once-per-launch prep ----
    int wtotal2 = 2 * L * H * H2;
    convert_weights_kernel<<<(wtotal2 + 255) / 256, 256, 0, stream>>>(W1, W2, W1t, W2t, L);
    embed_kernel<<<(N + 15) / 16, 256, 0, stream>>>(x, embW, embb, h0, N);

    hipMemsetAsync(deg, 0, (size_t)N * sizeof(int), stream);
    hipMemsetAsync(statsAll, 0, (size_t)L * 2 * H * sizeof(float), stream);
    // zero the tail rows of zg (rows N..T2*64) so MFMA sees finite values
    size_t tail = (size_t)T2 * 16384 - (size_t)N * 256;
    if (tail) hipMemsetAsync(zgb + (size_t)N * 256, 0, tail, stream);

    hist_kernel<<<(E + 255) / 256, 256, 0, stream>>>(dst, deg, E);
    scan_partial_kernel<<<numB, 256, 0, stream>>>(deg, bsum, N);
    scan_bsum_kernel<<<1, 256, 0, stream>>>(bsum, offp + N, numB);
    scan_apply_kernel<<<numB, 256, 0, stream>>>(deg, bsum, offp, cursor, N);
    fill_kernel<<<(E + 255) / 256, 256, 0, stream>>>(src, dst, cursor, srcl, E);

    int ggrid = (N * 16 + 255) / 256;
    int agrid = (int)(((size_t)N * (H / 8) + 255) / 256);

    for (int l = 0; l < L; ++l) {
        float* stats = statsAll + (size_t)l * 2 * H;
        const __bf16* hin = (l == 0) ? h0 : zpb;
        if (l == 0)
            gather_kernel<0><<<ggrid, 256, 0, stream>>>(hin, nullptr, offp, srcl, zgb, N);
        else
            gather_kernel<1><<<ggrid, 256, 0, stream>>>(hin, ss, offp, srcl, zgb, N);
        mlp_mfma_kernel<<<T2, 512, 0, stream>>>(
            zgb, zpb, W1t + (size_t)l * H * H2, b1 + (size_t)l * H2,
            W2t + (size_t)l * H * H2, b2 + (size_t)l * H, stats, N);
        bn_finalize_kernel<<<1, H, 0, stream>>>(
            stats, gamma + (size_t)l * H, beta + (size_t)l * H, ss, N);
    }
    bn_apply_kernel<<<agrid, 256, 0, stream>>>(zpb, ss, out, N);
}